// Round 10
// baseline (15658.125 us; speedup 1.0000x reference)
//
#include <hip/hip_runtime.h>

#define B_   64
#define T_   512
#define KIN  512
#define NH   512
#define KEFF 3072   // 6 segments x 512
#define NBLK 64
#define NTHR 512

typedef __attribute__((ext_vector_type(8))) short short8;
typedef __attribute__((ext_vector_type(4))) float f32x4;
typedef __attribute__((ext_vector_type(4))) unsigned int u32x4;

__device__ __forceinline__ unsigned short f2b(float f) {
    union { float f; unsigned int u; } v; v.f = f;
    unsigned int u = v.u;
    return (unsigned short)((u + 0x7FFFu + ((u >> 16) & 1u)) >> 16);
}
__device__ __forceinline__ float b2f(unsigned short h) {
    union { float f; unsigned int u; } v; v.u = ((unsigned int)h) << 16;
    return v.f;
}

// ---------------------------------------------------------------------------
// Prepack (proven): B' [n][keff] bf16. seg0-2: Whi,Whi,Wlo (H); seg3-5: X.
// ---------------------------------------------------------------------------
__global__ void prepack(const float* __restrict__ Wxz, const float* __restrict__ Whz,
                        const float* __restrict__ Wxr, const float* __restrict__ Whr,
                        const float* __restrict__ Wxh, const float* __restrict__ Whh,
                        unsigned short* __restrict__ Bzr, unsigned short* __restrict__ Bh) {
    int keff = blockIdx.x * 256 + threadIdx.x;
    int n    = blockIdx.y;
    int seg  = keff >> 9;
    int k    = keff & 511;
    const float* src;
    int c;
    if (n < 512)       { c = n;        src = (seg < 3) ? Whz : Wxz; }
    else if (n < 1024) { c = n - 512;  src = (seg < 3) ? Whr : Wxr; }
    else               { c = n - 1024; src = (seg < 3) ? Whh : Wxh; }
    float w = src[k * NH + c];
    unsigned short hi = f2b(w);
    unsigned short o  = (seg == 2 || seg == 5) ? f2b(w - b2f(hi)) : hi;
    if (n < 1024) Bzr[(size_t)n * KEFF + keff] = o;
    else          Bh[(size_t)(n - 1024) * KEFF + keff] = o;
}

// Coherent ops (proven): relaxed+agent -> sc-bit ops, no cache maintenance.
__device__ __forceinline__ unsigned int ald32(const unsigned int* p) {
    return __hip_atomic_load(p, __ATOMIC_RELAXED, __HIP_MEMORY_SCOPE_AGENT);
}
__device__ __forceinline__ void ast32(unsigned int* p, unsigned int v) {
    __hip_atomic_store(p, v, __ATOMIC_RELAXED, __HIP_MEMORY_SCOPE_AGENT);
}

// Raw barrier with LDS-drain (m201 pattern): lgkmcnt(0) + s_barrier + sched fence.
__device__ __forceinline__ void barx() {
    asm volatile("s_waitcnt lgkmcnt(0)" ::: "memory");
    __builtin_amdgcn_s_barrier();
    __builtin_amdgcn_sched_barrier(0);
}
__device__ __forceinline__ void vmdrain() {
    asm volatile("s_waitcnt vmcnt(0)" ::: "memory");
    __builtin_amdgcn_sched_barrier(0);
}
// Wave-uniform single-flag poll (X-crew only: its vmcnt(0) drain is harmless).
__device__ __forceinline__ void pollf(const unsigned int* p, unsigned int tgt) {
    while (ald32(p) < tgt) { }
    __builtin_amdgcn_sched_barrier(0);
}

__device__ __forceinline__ void cvt_x8(const float* xr, int kp, short8* ahi, short8* alo) {
    f32x4 x0 = *(const f32x4*)(xr + kp);
    f32x4 x1 = *(const f32x4*)(xr + kp + 4);
#pragma unroll
    for (int i = 0; i < 4; ++i) {
        unsigned short h0 = f2b(x0[i]);
        (*ahi)[i] = (short)h0; (*alo)[i] = (short)f2b(x0[i] - b2f(h0));
        unsigned short h1 = f2b(x1[i]);
        (*ahi)[4 + i] = (short)h1; (*alo)[4 + i] = (short)f2b(x1[i] - b2f(h1));
    }
}

__device__ __forceinline__ void unpackw(u32x4 w0, u32x4 w1, short8* ahi, short8* alo) {
    union { unsigned int u[4]; short8 v; } H, L;
    H.u[0] = __builtin_amdgcn_perm(w0[1], w0[0], 0x05040100u);
    H.u[1] = __builtin_amdgcn_perm(w0[3], w0[2], 0x05040100u);
    H.u[2] = __builtin_amdgcn_perm(w1[1], w1[0], 0x05040100u);
    H.u[3] = __builtin_amdgcn_perm(w1[3], w1[2], 0x05040100u);
    L.u[0] = __builtin_amdgcn_perm(w0[1], w0[0], 0x07060302u);
    L.u[1] = __builtin_amdgcn_perm(w0[3], w0[2], 0x07060302u);
    L.u[2] = __builtin_amdgcn_perm(w1[1], w1[0], 0x07060302u);
    L.u[3] = __builtin_amdgcn_perm(w1[3], w1[2], 0x07060302u);
    *ahi = H.v; *alo = L.v;
}

#define MFMA(a, b, c) __builtin_amdgcn_mfma_f32_16x16x32_bf16((a), (b), (c), 0, 0, 0)

// ---------------------------------------------------------------------------
// Persistent GRU — streamed slab dataflow (round-9 structure, race-fixed).
// FIX vs round 9: the initial stage(group 0) in each phase is now followed by
// vmdrain() BEFORE the barrier — global_load_lds is vmcnt-tracked, and barx
// only drains lgkmcnt, so the gi=0 GEMM could read slabs whose coherent
// loads were still in flight (absmax 0.206). Loop iterations already had the
// stage -> vmdrain -> barx ordering.
// ---------------------------------------------------------------------------
__global__ void __launch_bounds__(NTHR, 2) gru_seq(
    const float* __restrict__ X, const float* __restrict__ bz,
    const float* __restrict__ br, const float* __restrict__ bh,
    float* __restrict__ out,
    unsigned int* __restrict__ HP, unsigned int* __restrict__ RHP,
    const unsigned short* __restrict__ Bzr, const unsigned short* __restrict__ Bh,
    unsigned int* flags) {
    const int bid  = blockIdx.x;
    const int s    = bid & 15;
    const int g    = bid >> 4;
    const int tid  = threadIdx.x;
    const int wv   = tid >> 6;
    const int w4   = wv & 3;
    const bool xc  = wv >= 4;
    const int lane = tid & 63;
    const int fm   = lane & 15;
    const int fkc  = lane >> 4;
    const int fk   = fkc * 8;

    __shared__ unsigned int hbufH[16 * 512];   // 32 KB H(t-1), slab-major swz
    __shared__ unsigned int hbufR[16 * 512];   // 32 KB RH(t)
    __shared__ float xp1[2][4][16][16];        // 8 KB  P1 X-preacts (dbuf)
    __shared__ float xp2a[2][2][16][16];       // 4 KB  P2 X-preacts K-half 0
    __shared__ float xp2b[2][2][16][16];       // 4 KB  P2 X-preacts K-half 1
    __shared__ float zbufL[2][16][16];         // 2 KB  local Z (never global!)
    __shared__ float comb[2][256];             // 2 KB  P2 K-combine

    // P1 roles: gate = w4>>1 (0=z,1=r), half = w4&1; cols = s*32 + half*16+fm
    const int half = w4 & 1;
    const int gate = w4 >> 1;
    const int c1l  = half * 16 + fm;           // col-in-slab 0..31
    const unsigned short* Bp1 = Bzr + (size_t)(gate * 512 + s * 32 + c1l) * KEFF;
    const float bias1 = gate ? br[s * 32 + c1l] : bz[s * 32 + c1l];

    // P2 roles: ti = w4>>1 (col half), jh = w4&1 (K half)
    const int ti  = w4 >> 1, jh = w4 & 1;
    const int c2l = ti * 16 + fm;
    const int c2  = s * 32 + c2l;
    const unsigned short* Bp2 = Bh + (size_t)c2 * KEFF;
    const float bias2 = bh[c2];

    const int sw0 = (fkc * 32) ^ ((fm & 7) << 4);
    const int sw1 = sw0 ^ 16;

    unsigned int* HPg  = HP  + g * 8192;       // 16 slabs x 512 words
    unsigned int* RHPg = RHP + g * 8192;
    unsigned int* flg  = flags + g * 64;       // 16 flags, 256B-padded group

    const float* Xg = X + (size_t)(16 * g + fm) * (T_ * KIN);

    // stage slab (grp*4 + w4) of a global state buffer into LDS (coherent)
    auto stage = [&](const unsigned int* gsrc, unsigned int* ldst, int grp) {
        int slab = grp * 4 + w4;
        const char* sp = (const char*)gsrc + slab * 2048 + lane * 16;
        char* dp = (char*)ldst + slab * 2048;
        __builtin_amdgcn_global_load_lds((const unsigned int*)sp,
                                         (unsigned int*)dp, 16, 0, 0x11);
        __builtin_amdgcn_global_load_lds((const unsigned int*)(sp + 1024),
                                         (unsigned int*)(dp + 1024), 16, 0, 0x11);
    };
    auto gemmH = [&](const unsigned int* lbuf, const unsigned short* Bp,
                     int slab, f32x4& a) {
        const char* sb = (const char*)lbuf + slab * 2048 + fm * 128;
        u32x4 w0 = *(const u32x4*)(sb + sw0);
        u32x4 w1 = *(const u32x4*)(sb + sw1);
        short8 ahi, alo; unpackw(w0, w1, &ahi, &alo);
        const unsigned short* Bk = Bp + slab * 32 + fk;
        short8 b0 = *(const short8*)(Bk);
        short8 b1 = *(const short8*)(Bk + 512);
        short8 b2 = *(const short8*)(Bk + 1024);
        a = MFMA(ahi, b0, a); a = MFMA(alo, b1, a); a = MFMA(ahi, b2, a);
    };
    auto xg1p = [&](int gi, int tt, int buf, f32x4& a) {  // 4 j-iters of X@Wzr
        const float* xr = Xg + (size_t)tt * KIN;
#pragma unroll
        for (int q = 0; q < 4; ++q) {
            int kp = (gi * 4 + q) * 32 + fk;
            short8 xhi, xlo; cvt_x8(xr, kp, &xhi, &xlo);
            short8 b3 = *(const short8*)(Bp1 + 1536 + kp);
            short8 b4 = *(const short8*)(Bp1 + 2048 + kp);
            short8 b5 = *(const short8*)(Bp1 + 2560 + kp);
            a = MFMA(xhi, b3, a); a = MFMA(xlo, b4, a); a = MFMA(xhi, b5, a);
        }
        if (gi == 3) {
#pragma unroll
            for (int jj = 0; jj < 4; ++jj) xp1[buf][w4][fkc * 4 + jj][fm] = a[jj];
        }
    };
    auto xg2p = [&](int gi, int tt, int buf, f32x4& a) {  // 2 j-iters of X@Wh
        const float* xr = Xg + (size_t)tt * KIN;
#pragma unroll
        for (int q = 0; q < 2; ++q) {
            int kp = (jh * 8 + gi * 2 + q) * 32 + fk;
            short8 xhi, xlo; cvt_x8(xr, kp, &xhi, &xlo);
            short8 b3 = *(const short8*)(Bp2 + 1536 + kp);
            short8 b4 = *(const short8*)(Bp2 + 2048 + kp);
            short8 b5 = *(const short8*)(Bp2 + 2560 + kp);
            a = MFMA(xhi, b3, a); a = MFMA(xlo, b4, a); a = MFMA(xhi, b5, a);
        }
        if (gi == 3) {
            float (*dst)[16][16] = jh ? xp2b[buf] : xp2a[buf];
#pragma unroll
            for (int jj = 0; jj < 4; ++jj) dst[ti][fkc * 4 + jj][fm] = a[jj];
        }
    };

    // prologue: X-preacts for t=0 into buf 0
    if (xc) {
        f32x4 a1 = {0.f, 0.f, 0.f, 0.f}, a2 = {0.f, 0.f, 0.f, 0.f};
        for (int gi = 0; gi < 4; ++gi) { xg1p(gi, 0, 0, a1); xg2p(gi, 0, 0, a2); }
    }
    barx();

    for (int t = 0; t < T_; ++t) {
        const unsigned int ep = (unsigned int)t * 2u;
        const int bufc = t & 1, bufn = bufc ^ 1;
        const int tn = t + 1;
        // ========================= phase 1: Z and R =========================
        f32x4 acc = {0.f, 0.f, 0.f, 0.f}, ax1 = {0.f, 0.f, 0.f, 0.f};
        if (xc) pollf(flg + w4, ep);                  // H slabs grp0
        barx();                                       // slotA
        if (!xc) { stage(HPg, hbufH, 0); vmdrain(); } // FIX: drain before barrier
        else pollf(flg + 4 + w4, ep);                 // grp1
        barx();                                       // slotB
        for (int gi = 0; gi < 4; ++gi) {
            if (!xc) {
                if (gi < 3) stage(HPg, hbufH, gi + 1);
#pragma unroll
                for (int q = 0; q < 4; ++q) gemmH(hbufH, Bp1, gi * 4 + q, acc);
                if (gi < 3) vmdrain();
            } else {
                if (gi < 2) pollf(flg + 4 * (gi + 2) + w4, ep);
                if (tn < T_) xg1p(gi, tn, bufn, ax1);
            }
            barx();                                   // slot gi
        }
        if (!xc) {                                    // P1 epilogue
#pragma unroll
            for (int jj = 0; jj < 4; ++jj) {
                int mr = fkc * 4 + jj;
                float pre = acc[jj] + xp1[bufc][w4][mr][fm] + bias1;
                float gv  = 1.f / (1.f + __expf(-pre));
                if (gate == 0) {
                    zbufL[half][mr][fm] = gv;         // Z stays local
                } else {
                    unsigned int hw = hbufH[s * 512 + mr * 32 +
                                            (c1l ^ ((mr & 7) << 2))];
                    float h  = b2f((unsigned short)(hw & 0xffffu)) +
                               b2f((unsigned short)(hw >> 16));
                    float rh = gv * h;
                    unsigned short hi = f2b(rh);
                    unsigned short lo = f2b(rh - b2f(hi));
                    ast32(RHPg + s * 512 + mr * 32 + (c1l ^ ((mr & 7) << 2)),
                          (unsigned int)hi | ((unsigned int)lo << 16));
                }
            }
            if (gate) vmdrain();                      // RH publish acked
        }
        barx();                                       // P1 epilogue barrier
        if (tid == 0) ast32(flg + s, ep + 1u);        // RH slab s ready
        // ========================= phase 2: h~ and H ========================
        f32x4 acc2 = {0.f, 0.f, 0.f, 0.f}, ax2 = {0.f, 0.f, 0.f, 0.f};
        if (xc) pollf(flg + w4, ep + 1u);             // RH slabs grp0
        barx();                                       // slotA
        if (!xc) { stage(RHPg, hbufR, 0); vmdrain(); }// FIX: drain before barrier
        else pollf(flg + 4 + w4, ep + 1u);            // grp1
        barx();                                       // slotB
        for (int gi = 0; gi < 4; ++gi) {
            if (!xc) {
                if (gi < 3) stage(RHPg, hbufR, gi + 1);
                if ((gi >> 1) == jh) {
#pragma unroll
                    for (int q = 0; q < 4; ++q) gemmH(hbufR, Bp2, gi * 4 + q, acc2);
                }
                if (gi < 3) vmdrain();
            } else {
                if (gi < 2) pollf(flg + 4 * (gi + 2) + w4, ep + 1u);
                if (tn < T_) xg2p(gi, tn, bufn, ax2);
            }
            barx();                                   // slot gi
        }
        if (!xc && jh == 1) {                         // K-half 1 -> comb
#pragma unroll
            for (int jj = 0; jj < 4; ++jj)
                comb[ti][(fkc * 4 + jj) * 16 + fm] = acc2[jj];
        }
        barx();                                       // comb barrier
        if (!xc && jh == 0) {                         // blend + publish
#pragma unroll
            for (int jj = 0; jj < 4; ++jj) {
                int mr = fkc * 4 + jj;
                unsigned int hw = hbufH[s * 512 + mr * 32 +
                                        (c2l ^ ((mr & 7) << 2))];
                float h   = b2f((unsigned short)(hw & 0xffffu)) +
                            b2f((unsigned short)(hw >> 16));
                float pre = acc2[jj] + comb[ti][mr * 16 + fm] +
                            xp2a[bufc][ti][mr][fm] + xp2b[bufc][ti][mr][fm] + bias2;
                float e   = __expf(-2.f * pre);
                float ht  = 2.f / (1.f + e) - 1.f;    // tanh
                float z   = zbufL[ti][mr][fm];
                float hn  = z * h + (1.f - z) * ht;
                int mg = 16 * g + mr;
                out[(size_t)mg * (T_ * NH) + (size_t)t * NH + c2] = hn;
                if (t == T_ - 1)
                    out[(size_t)B_ * T_ * NH + mg * NH + c2] = hn;
                unsigned short hi = f2b(hn);
                unsigned short lo = f2b(hn - b2f(hi));
                ast32(HPg + s * 512 + mr * 32 + (c2l ^ ((mr & 7) << 2)),
                      (unsigned int)hi | ((unsigned int)lo << 16));
            }
            vmdrain();                                // H publish acked
        }
        barx();                                       // P2 epilogue barrier
        if (tid == 0) ast32(flg + s, ep + 2u);        // H slab s ready
    }
}

extern "C" void kernel_launch(void* const* d_in, const int* in_sizes, int n_in,
                              void* d_out, int out_size, void* d_ws, size_t ws_size,
                              hipStream_t stream) {
    (void)in_sizes; (void)n_in; (void)out_size; (void)ws_size;
    const float* X   = (const float*)d_in[0];
    const float* Wxz = (const float*)d_in[1];
    const float* Whz = (const float*)d_in[2];
    const float* bz  = (const float*)d_in[3];
    const float* Wxr = (const float*)d_in[4];
    const float* Whr = (const float*)d_in[5];
    const float* br  = (const float*)d_in[6];
    const float* Wxh = (const float*)d_in[7];
    const float* Whh = (const float*)d_in[8];
    const float* bh  = (const float*)d_in[9];
    float* out = (float*)d_out;

    char* ws = (char*)d_ws;
    unsigned int* flags = (unsigned int*)ws;                   // 4 x 256 B
    unsigned int* HP  = (unsigned int*)(ws + 4096);            // 4 x 32 KB slab-major
    unsigned int* RHP = (unsigned int*)(ws + 4096 + 131072);   // 4 x 32 KB
    unsigned short* Bzr = (unsigned short*)(ws + (1 << 20));   // 6.3 MB
    unsigned short* Bh  = Bzr + (size_t)1024 * KEFF;           // 3.2 MB

    hipMemsetAsync(d_ws, 0, 1 << 20, stream);   // flags + H0 = 0
    prepack<<<dim3(12, 1536), 256, 0, stream>>>(Wxz, Whz, Wxr, Whr, Wxh, Whh, Bzr, Bh);
    gru_seq<<<NBLK, NTHR, 0, stream>>>(X, bz, br, bh, out, HP, RHP, Bzr, Bh, flags);
}